// Round 18
// baseline (426.404 us; speedup 1.0000x reference)
//
#include <hip/hip_runtime.h>
#include <stdint.h>
#include <math.h>

typedef __attribute__((ext_vector_type(8))) short short8;
typedef __attribute__((ext_vector_type(4))) float floatx4;

#define IMGN 448
#define HW   200704
#define NBATCH 64
#define NBINS 36

#define MFMA(a, b, c) __builtin_amdgcn_mfma_f32_16x16x32_bf16((a), (b), (c), 0, 0, 0)

// counted-vmcnt pipeline barriers (asm so the compiler can't force vmcnt(0))
#define WAITBAR6() asm volatile("s_waitcnt vmcnt(6)\ns_barrier" ::: "memory")
#define WAITBAR0() asm volatile("s_waitcnt vmcnt(0)\ns_barrier" ::: "memory")
#define ENDBAR()   asm volatile("s_waitcnt lgkmcnt(0)\ns_barrier" ::: "memory")

// ---------------- workspace map (bytes) ----------------
#define WS_WIN   0u
#define WS_BINS  4096u
#define WS_TS    24576u
#define WS_BIDX  32768u
#define WS_TW    1048576u
#define TWSZ     401408u      // 28*14*64*16
#define WS_W     4194304u
#define WSZ      1179648u     // 48*24*64*16
#define WS_REG1  16777216u
#define GSZ      25690112u    // 1792*14*64*16
#define CBSZ     13762560u    // 960*14*64*16
#define XSZ      25165824u    // 1024*24*64*16
#define WS_REG2  75497472u
// REG1: G frags (2 x GSZ) -> xd frags (2 x XSZ, after rows)
// REG2: cols-B frags (4 x CBSZ, written by k_rows) -> h frags (2 x XSZ, after cols)

// ---------------- threefry2x32 (JAX partitionable) ----------------
__host__ __device__ __forceinline__ uint32_t rotl32(uint32_t v, int r) {
  return (v << r) | (v >> (32 - r));
}
__host__ __device__ __forceinline__ void tf2x32(uint32_t k0, uint32_t k1,
                                                uint32_t x0, uint32_t x1,
                                                uint32_t &o0, uint32_t &o1) {
  uint32_t k2 = k0 ^ k1 ^ 0x1BD11BDAu;
  uint32_t v0 = x0 + k0, v1 = x1 + k1;
#define TFR(r) { v0 += v1; v1 = rotl32(v1, r); v1 ^= v0; }
  TFR(13) TFR(15) TFR(26) TFR(6)   v0 += k1; v1 += k2 + 1u;
  TFR(17) TFR(29) TFR(16) TFR(24)  v0 += k2; v1 += k0 + 2u;
  TFR(13) TFR(15) TFR(26) TFR(6)   v0 += k0; v1 += k1 + 3u;
  TFR(17) TFR(29) TFR(16) TFR(24)  v0 += k1; v1 += k2 + 4u;
  TFR(13) TFR(15) TFR(26) TFR(6)   v0 += k2; v1 += k0 + 5u;
#undef TFR
  o0 = v0; o1 = v1;
}
__device__ __forceinline__ float tf_uniform(uint32_t k0, uint32_t k1, uint32_t idx) {
  uint32_t a, b;
  tf2x32(k0, k1, 0u, idx, a, b);
  uint32_t bits = a ^ b;
  return __uint_as_float((bits >> 9) | 0x3F800000u) - 1.0f;
}

// ---------------- bf16 split helpers ----------------
__device__ __forceinline__ unsigned short bf16rne(float v) {
  unsigned u = __float_as_uint(v);
  return (unsigned short)((u + 0x7fffu + ((u >> 16) & 1u)) >> 16);
}
__device__ __forceinline__ void split2(float v, unsigned short &h, unsigned short &l) {
  h = bf16rne(v);
  float fh = __uint_as_float(((unsigned)h) << 16);
  l = bf16rne(v - fh);
}

// branch-free erf (Abramowitz-Stegun 7.1.26, |abs err| <= 1.5e-7)
__device__ __forceinline__ float fast_erf(float x) {
  float ax = fabsf(x);
  float t = 1.0f / (1.0f + 0.3275911f * ax);
  float p = t * (0.254829592f + t * (-0.284496736f + t * (1.421413741f +
            t * (-1.453152027f + t * 1.061405429f))));
  float y = 1.0f - p * __expf(-ax * ax);
  return __uint_as_float((__float_as_uint(y) & 0x7fffffffu) |
                         (__float_as_uint(x) & 0x80000000u));
}

// async 16B/lane global->LDS; lds dst must be wave-uniform base (HW adds lane*16)
__device__ __forceinline__ void gload16(const void *g, void *l) {
  __builtin_amdgcn_global_load_lds(
      (const __attribute__((address_space(1))) unsigned int *)g,
      (__attribute__((address_space(3))) unsigned int *)l, 16, 0, 0);
}

// ---------------- prep ----------------
__global__ __launch_bounds__(256) void k_prep(float *__restrict__ win,
                                              double *__restrict__ bins,
                                              uint8_t *__restrict__ bidx) {
  int t = blockIdx.x * 256 + threadIdx.x;
  int a = t / IMGN, b = t % IMGN;
  double yy = (double)((a + 224) % IMGN) - 223.5;
  double xx = (double)((b + 224) % IMGN) - 223.5;
  double r2 = xx * xx + yy * yy;
  uint8_t idx = 255;
  if (r2 >= 249.76125 && r2 <= 90163.81125) {
    double th = atan2(yy, xx);
    if (th < 0.0) th += 6.283185307179586476925286766559;
    int i = (int)(th / 0.17453292519943295769236907684886);
    if (i > 35) i = 35;
    if (i < 0) i = 0;
    idx = (uint8_t)i;
  }
  bidx[t] = idx;
  if (t < IMGN) {
    double ang = 6.283185307179586476925286766559 * (double)t / 448.0;
    win[t] = (float)(0.5 - 0.5 * cos(ang));
  }
  if (t < NBATCH * NBINS) bins[t] = 0.0;
}

// ---------------- twiddle frag matrices (4) ----------------
__global__ __launch_bounds__(256) void k_tw(short8 *__restrict__ tch, short8 *__restrict__ tcl,
                                            short8 *__restrict__ tsh, short8 *__restrict__ tsl) {
  int wid = blockIdx.x * 256 + threadIdx.x;   // 25088 = 28*14*64
  int lane = wid & 63;
  int tmp = wid >> 6;
  int kb = tmp % 14, mb = tmp / 14;
  int m = mb * 16 + (lane & 15);
  int k0 = kb * 32 + (lane >> 4) * 8;
  short8 ch, cl, sh, sl;
#pragma unroll
  for (int e = 0; e < 8; ++e) {
    int mm = (m * (k0 + e)) % IMGN;
    double ang = -6.283185307179586476925286766559 * (double)mm / 448.0;
    float c = (float)cos(ang), s = (float)sin(ang);
    unsigned short h, l;
    split2(c, h, l); ch[e] = (short)h; cl[e] = (short)l;
    split2(s, h, l); sh[e] = (short)h; sl[e] = (short)l;
  }
  tch[wid] = ch; tcl[wid] = cl; tsh[wid] = sh; tsl[wid] = sl;
}

// ---------------- weight frag matrices ----------------
__global__ __launch_bounds__(256) void k_wconv(const float *__restrict__ w1, const float *__restrict__ w2,
                                               short8 *__restrict__ w1h, short8 *__restrict__ w1l,
                                               short8 *__restrict__ w2h, short8 *__restrict__ w2l) {
  int wid = blockIdx.x * 256 + threadIdx.x;   // 73728 = 48*24*64
  const float *src = blockIdx.y ? w2 : w1;
  short8 *dh = blockIdx.y ? w2h : w1h;
  short8 *dl = blockIdx.y ? w2l : w1l;
  int lane = wid & 63;
  int tmp = wid >> 6;
  int kb = tmp % 24, nb = tmp / 24;
  int n = nb * 16 + (lane & 15);
  int k0 = kb * 32 + (lane >> 4) * 8;
  const float *p = src + (size_t)n * 768 + k0;
  short8 vh, vl;
#pragma unroll
  for (int e = 0; e < 8; ++e) {
    unsigned short h, l;
    split2(p[e], h, l);
    vh[e] = (short)h; vl[e] = (short)l;
  }
  dh[wid] = vh; dl[wid] = vl;
}

// ---------------- windowed grayscale frag matrices ----------------
__global__ __launch_bounds__(256) void k_gprep(const float *__restrict__ img, const float *__restrict__ win,
                                               short8 *__restrict__ gh, short8 *__restrict__ gl) {
  int wid = blockIdx.x * 256 + threadIdx.x;   // 1605632 = 1792*14*64
  int lane = wid & 63;
  int tmp = wid >> 6;
  int kb = tmp % 14, nb = tmp / 14;
  int n = nb * 16 + (lane & 15);              // n = b*448 + y
  int b = n / 448, y = n % 448;
  int x0 = kb * 32 + (lane >> 4) * 8;
  const float *p = img + (size_t)b * 3 * HW + y * IMGN + x0;
  float wy = win[y];
  short8 vh, vl;
#pragma unroll
  for (int e = 0; e < 8; ++e) {
    float r = p[e], g = p[HW + e], bl = p[2 * HW + e];
    float t0 = (r * 0.229f + 0.485f) * 0.2989f;
    float t1 = (g * 0.224f + 0.456f) * 0.587f;
    float t2 = (bl * 0.225f + 0.406f) * 0.114f;
    float v = ((t0 + t1) + t2) * wy * win[x0 + e];
    unsigned short h, l;
    split2(v, h, l);
    vh[e] = (short)h; vl[e] = (short)l;
  }
  gh[wid] = vh; gl[wid] = vl;
}

// ---------------- rows GEMM: 2 mtiles per wave (48 MFMA/iter), 256 thr -------
// grid 896 = 2 mtg * 448 ntg, mtg fastest (shares B panel)
__global__ __launch_bounds__(256) void k_rows(const short8 *__restrict__ tch, const short8 *__restrict__ tcl,
                                              const short8 *__restrict__ tsh, const short8 *__restrict__ tsl,
                                              const short8 *__restrict__ gh, const short8 *__restrict__ gl,
                                              short8 *__restrict__ crh, short8 *__restrict__ crl,
                                              short8 *__restrict__ cih, short8 *__restrict__ cil) {
  __shared__ short8 S[512];    // B: 2 mats x 4 nt (chunks 0..7)
  int orig = blockIdx.x;
  int swz = (orig & 7) * 112 + (orig >> 3);
  int mtg = swz & 1, ntg = swz >> 1;
  int tid = threadIdx.x;
  int lane = tid & 63, w = tid >> 6;
  int g = lane >> 4, c = lane & 15;
  int mt0 = mtg * 8 + w * 2;
  floatx4 sc0[4] = {}, ss0[4] = {}, sc1[4] = {}, ss1[4] = {};
  for (int kb = 0; kb < 14; ++kb) {
#pragma unroll
    for (int i = 0; i < 2; ++i) {
      int ch = w * 2 + i;                 // 0..7: mat = ch>>2, nt = ch&3
      const short8 *m0 = (ch >> 2) ? gl : gh;
      int row = ntg * 4 + (ch & 3);
      gload16(m0 + ((size_t)row * 14 + kb) * 64 + lane, (char *)S + ch * 1024);
    }
    int ao0 = (mt0 * 14 + kb) * 64 + lane;
    int ao1 = ao0 + 14 * 64;
    short8 c0 = tch[ao0], l0 = tcl[ao0], s0 = tsh[ao0], z0 = tsl[ao0];
    short8 c1 = tch[ao1], l1 = tcl[ao1], s1 = tsh[ao1], z1 = tsl[ao1];
    __syncthreads();
#pragma unroll
    for (int nt = 0; nt < 4; ++nt) {
      short8 bh = S[nt * 64 + lane];
      short8 bl = S[(4 + nt) * 64 + lane];
      sc0[nt] = MFMA(c0, bh, sc0[nt]);
      sc0[nt] = MFMA(c0, bl, sc0[nt]);
      sc0[nt] = MFMA(l0, bh, sc0[nt]);
      ss0[nt] = MFMA(s0, bh, ss0[nt]);
      ss0[nt] = MFMA(s0, bl, ss0[nt]);
      ss0[nt] = MFMA(z0, bh, ss0[nt]);
      sc1[nt] = MFMA(c1, bh, sc1[nt]);
      sc1[nt] = MFMA(c1, bl, sc1[nt]);
      sc1[nt] = MFMA(l1, bh, sc1[nt]);
      ss1[nt] = MFMA(s1, bh, ss1[nt]);
      ss1[nt] = MFMA(s1, bl, ss1[nt]);
      ss1[nt] = MFMA(z1, bh, ss1[nt]);
    }
    __syncthreads();
  }
  // epilogue: split in-register, scatter into cols-B frag layout (x2 mtiles)
#define R_EPI(SC, SS, MT)                                                      \
  {                                                                            \
    _Pragma("unroll") for (int nt = 0; nt < 4; ++nt) {                         \
      int nrow = (ntg * 4 + nt) * 16 + c;                                      \
      int b = nrow / 448, y = nrow % 448;                                      \
      int kb2 = y >> 5;                                                        \
      int lofs = 16 * ((y & 31) >> 3);                                         \
      int e2 = y & 7;                                                          \
      _Pragma("unroll") for (int r = 0; r < 4; ++r) {                          \
        int v = (MT) * 16 + 4 * g + r;                                         \
        if (v < 240) {                                                         \
          int n2 = b * 240 + v;                                                \
          size_t word = ((size_t)(n2 >> 4) * 14 + kb2) * 64 + (n2 & 15) + lofs;\
          unsigned short h, l;                                                 \
          split2(SC[nt][r], h, l);                                             \
          ((unsigned short *)crh)[word * 8 + e2] = h;                          \
          ((unsigned short *)crl)[word * 8 + e2] = l;                          \
          split2(SS[nt][r], h, l);                                             \
          ((unsigned short *)cih)[word * 8 + e2] = h;                          \
          ((unsigned short *)cil)[word * 8 + e2] = l;                          \
        }                                                                      \
      }                                                                        \
    }                                                                          \
  }
  R_EPI(sc0, ss0, mt0)
  R_EPI(sc1, ss1, mt0 + 1)
#undef R_EPI
}

// ---------------- cols GEMM: 256 thr, 4 waves, 2mt x 2nt per wave ------------
// grid 1680 = 7 mtg * 240 ntg, mtg fastest (shares B panel)
// Per wave-phase: 8 B-LDS chunk reads feed 48 MFMAs (vs 16 reads before)
__global__ __launch_bounds__(256) void k_cols(const short8 *__restrict__ tch, const short8 *__restrict__ tcl,
                                              const short8 *__restrict__ tsh, const short8 *__restrict__ tsl,
                                              const short8 *__restrict__ crh, const short8 *__restrict__ crl,
                                              const short8 *__restrict__ cih, const short8 *__restrict__ cil,
                                              const uint8_t *__restrict__ bidx, double *__restrict__ bins) {
  __shared__ short8 S[1024];   // B: 4 mats x 4 nt (chunks 0..15)
  __shared__ double lb[72];
  int orig = blockIdx.x;
  int swz = (orig & 7) * 210 + (orig >> 3);
  int mtg = swz % 7, ntg = swz / 7;
  int tid = threadIdx.x;
  if (tid < 72) lb[tid] = 0.0;
  int lane = tid & 63, w = tid >> 6;
  int g = lane >> 4, c = lane & 15;
  int wm = w >> 1, wn = w & 1;
  int mt0 = mtg * 4 + wm * 2;        // wave's mtiles: mt0, mt0+1
  int ntb = wn * 2;                  // wave's nt offset within block tile
  int nt0 = ntg * 4;
  floatx4 cc0[2] = {}, sc0[2] = {}, ss0[2] = {}, cs0[2] = {};
  floatx4 cc1[2] = {}, sc1[2] = {}, ss1[2] = {}, cs1[2] = {};
  for (int kb = 0; kb < 14; ++kb) {
#pragma unroll
    for (int i = 0; i < 4; ++i) {
      int ch = w * 4 + i;              // 0..15: mat = ch>>2, nt = ch&3
      int sel = ch >> 2;
      const short8 *m0 = sel == 0 ? crh : sel == 1 ? crl : sel == 2 ? cih : cil;
      int row = nt0 + (ch & 3);
      gload16(m0 + ((size_t)row * 14 + kb) * 64 + lane, (char *)S + ch * 1024);
    }
    int ao = (mt0 * 14 + kb) * 64 + lane;
    short8 c0 = tch[ao], l0 = tcl[ao], s0 = tsh[ao], z0 = tsl[ao];
    short8 c1 = tch[ao + 896], l1 = tcl[ao + 896], s1 = tsh[ao + 896], z1 = tsl[ao + 896];
    __syncthreads();
#pragma unroll
    for (int nt = 0; nt < 2; ++nt) {
      int ntl = ntb + nt;
      short8 brh = S[ntl * 64 + lane];
      short8 brl = S[(4 + ntl) * 64 + lane];
      short8 bih = S[(8 + ntl) * 64 + lane];
      short8 bil = S[(12 + ntl) * 64 + lane];
      cc0[nt] = MFMA(c0, brh, cc0[nt]);
      cc0[nt] = MFMA(c0, brl, cc0[nt]);
      cc0[nt] = MFMA(l0, brh, cc0[nt]);
      sc0[nt] = MFMA(s0, brh, sc0[nt]);
      sc0[nt] = MFMA(s0, brl, sc0[nt]);
      sc0[nt] = MFMA(z0, brh, sc0[nt]);
      ss0[nt] = MFMA(s0, bih, ss0[nt]);
      ss0[nt] = MFMA(s0, bil, ss0[nt]);
      ss0[nt] = MFMA(z0, bih, ss0[nt]);
      cs0[nt] = MFMA(c0, bih, cs0[nt]);
      cs0[nt] = MFMA(c0, bil, cs0[nt]);
      cs0[nt] = MFMA(l0, bih, cs0[nt]);
      cc1[nt] = MFMA(c1, brh, cc1[nt]);
      cc1[nt] = MFMA(c1, brl, cc1[nt]);
      cc1[nt] = MFMA(l1, brh, cc1[nt]);
      sc1[nt] = MFMA(s1, brh, sc1[nt]);
      sc1[nt] = MFMA(s1, brl, sc1[nt]);
      sc1[nt] = MFMA(z1, brh, sc1[nt]);
      ss1[nt] = MFMA(s1, bih, ss1[nt]);
      ss1[nt] = MFMA(s1, bil, ss1[nt]);
      ss1[nt] = MFMA(z1, bih, ss1[nt]);
      cs1[nt] = MFMA(c1, bih, cs1[nt]);
      cs1[nt] = MFMA(c1, bil, cs1[nt]);
      cs1[nt] = MFMA(l1, bih, cs1[nt]);
    }
    __syncthreads();
  }
  // binning epilogue with per-thread 4-entry MRU cache (static reg indexing)
  int base_b = (ntg * 64) / 240;
  int cb0 = -1, cb1 = -1, cb2 = -1, cb3 = -1;
  double cv0 = 0.0, cv1 = 0.0, cv2 = 0.0, cv3 = 0.0;
#define PUTBIN(slot_, val_)                                                    \
  { int _s = (slot_); double _v = (val_);                                      \
    if (_s == cb0) cv0 += _v;                                                  \
    else if (_s == cb1) cv1 += _v;                                             \
    else if (_s == cb2) cv2 += _v;                                             \
    else if (_s == cb3) cv3 += _v;                                             \
    else {                                                                     \
      if (cb3 >= 0) atomicAdd(&lb[cb3], cv3);                                  \
      cb3 = cb2; cv3 = cv2; cb2 = cb1; cv2 = cv1;                              \
      cb1 = cb0; cv1 = cv0; cb0 = _s; cv0 = _v;                                \
    } }
#define C_EPI(CC, SC, SS, CS, MT)                                              \
  {                                                                            \
    _Pragma("unroll") for (int nt = 0; nt < 2; ++nt) {                         \
      int n = (nt0 + ntb + nt) * 16 + c;                                       \
      int v = n % 240;                                                         \
      int bloc = n / 240 - base_b;                                             \
      if (v < 225) {                                                           \
        _Pragma("unroll") for (int r = 0; r < 4; ++r) {                        \
          int u = (MT) * 16 + 4 * g + r;                                       \
          float frv = CC[nt][r] - SS[nt][r];                                   \
          float fiv = SC[nt][r] + CS[nt][r];                                   \
          double P = (double)frv * frv + (double)fiv * fiv;                    \
          int i1 = bidx[u * IMGN + v];                                         \
          if (i1 < 36) PUTBIN(bloc * 36 + i1, P);                              \
          if (v >= 1 && v <= 223) {                                            \
            int i2 = bidx[((IMGN - u) % IMGN) * IMGN + (IMGN - v)];            \
            if (i2 < 36) PUTBIN(bloc * 36 + i2, P);                            \
          }                                                                    \
        }                                                                      \
      }                                                                        \
    }                                                                          \
  }
  C_EPI(cc0, sc0, ss0, cs0, mt0)
  C_EPI(cc1, sc1, ss1, cs1, mt0 + 1)
#undef C_EPI
  if (cb0 >= 0) atomicAdd(&lb[cb0], cv0);
  if (cb1 >= 0) atomicAdd(&lb[cb1], cv1);
  if (cb2 >= 0) atomicAdd(&lb[cb2], cv2);
  if (cb3 >= 0) atomicAdd(&lb[cb3], cv3);
#undef PUTBIN
  __syncthreads();
  if (tid < 72) {
    int bb = base_b + tid / 36;
    if (bb < NBATCH && lb[tid] != 0.0) atomicAdd(&bins[bb * NBINS + (tid % 36)], lb[tid]);
  }
}

// ---------------- entropy -> ape -> drop prob ----------------
__global__ void k_probs(const double *__restrict__ bins, float *__restrict__ ts) {
  int b = threadIdx.x;
  if (b >= NBATCH) return;
  double T = 0.0;
  for (int i = 0; i < NBINS; ++i) T += bins[b * NBINS + i];
  double H = 0.0;
  for (int i = 0; i < NBINS; ++i) {
    double p = bins[b * NBINS + i] / (T + 1e-12);
    H -= p * log(p + 1e-12);
  }
  double ape = H / 3.5835189384561099;
  if (ape > 1.0) ape = 1.0;
  if (ape < 0.0) ape = 0.0;
  if (T <= 1e-12) ape = 0.0;
  double adj = tanh((0.78 - ape) * 4.0);
  double drop = (adj >= 0.0) ? (0.3 + adj * 0.3) : (0.3 + adj * 0.2);
  if (drop < 0.1) drop = 0.1;
  if (drop > 0.6) drop = 0.6;
  float p32 = (float)drop;
  ts[b] = 1.0f - p32;
  ts[NBATCH + b] = 1.0f / (1.0f - p32 + 1e-8f);
}

// ---------------- dropout(x) -> A-frag split mats ----------------
__global__ __launch_bounds__(256) void k_dropfrag(const float *__restrict__ x, const float *__restrict__ ts,
                                                  short8 *__restrict__ xh, short8 *__restrict__ xl,
                                                  uint32_t k0, uint32_t k1) {
  int wid = blockIdx.x * 256 + threadIdx.x;   // 1572864 = 1024*24*64
  int lane = wid & 63;
  int tmp = wid >> 6;
  int kb = tmp % 24, mb = tmp / 24;
  int m = mb * 16 + (lane & 15);
  int d0 = kb * 32 + (lane >> 4) * 8;
  int bi = m >> 8;
  float t = ts[bi], s = ts[NBATCH + bi];
  const float *p = x + (size_t)m * 768 + d0;
  short8 vh, vl;
#pragma unroll
  for (int e = 0; e < 8; ++e) {
    uint32_t idx = (uint32_t)m * 768u + (uint32_t)(d0 + e);
    float u = tf_uniform(k0, k1, idx);
    float v = (u < t) ? p[e] * s : 0.0f;
    unsigned short h, l;
    split2(v, h, l);
    vh[e] = (short)h; vl[e] = (short)l;
  }
  xh[wid] = vh; xl[wid] = vl;
}

// ---------------- MLP GEMM: 2 mtiles/wave, counted-vmcnt 2-deep pipeline -----
// grid 1536 = 12 ntg * 128 mtg, ntg fastest (shares A panel); 256 thr (4 waves)
template <int MODE>
__global__ __launch_bounds__(256) void k_mlp(const short8 *__restrict__ ah, const short8 *__restrict__ al,
                                             const short8 *__restrict__ bh, const short8 *__restrict__ bl,
                                             const float *__restrict__ ts, float *__restrict__ out,
                                             short8 *__restrict__ oh, short8 *__restrict__ ol,
                                             uint32_t k0, uint32_t k1) {
  __shared__ short8 S[2][512];   // B: 2 mats x 4 nt per buffer
  int orig = blockIdx.x;
  int swz = (orig & 7) * 192 + (orig >> 3);
  int ntg = swz % 12, mtg = swz / 12;
  int tid = threadIdx.x;
  int lane = tid & 63, w = tid >> 6;
  int g = lane >> 4, c = lane & 15;
  int mt0 = mtg * 8 + w * 2;    // this wave's 2 mtiles: mt0, mt0+1
  int nt0 = ntg * 4;
  floatx4 acc0[4] = {}, acc1[4] = {};
  short8 aAh0, aAl0, aAh1, aAl1, aBh0, aBl0, aBh1, aBl1;

#define M_STAGE(buf, kb) { \
  _Pragma("unroll") for (int i = 0; i < 2; ++i) { \
    int ch = w * 2 + i; \
    const short8 *m0 = (ch >> 2) ? bl : bh; \
    int row = nt0 + (ch & 3); \
    gload16(m0 + ((size_t)row * 24 + (kb)) * 64 + lane, (char *)&S[buf][0] + ch * 1024); } }
#define M_LOADA(p, kb) { int ao = (mt0 * 24 + (kb)) * 64 + lane; \
  p##h0 = ah[ao]; p##l0 = al[ao]; \
  p##h1 = ah[ao + 24 * 64]; p##l1 = al[ao + 24 * 64]; }
#define M_COMPUTE(buf, p) { const short8 *Sc = &S[buf][0]; \
  _Pragma("unroll") for (int nt = 0; nt < 4; ++nt) { \
    short8 b_h = Sc[nt * 64 + lane]; \
    short8 b_l = Sc[(4 + nt) * 64 + lane]; \
    acc0[nt] = MFMA(p##h0, b_h, acc0[nt]); \
    acc0[nt] = MFMA(p##h0, b_l, acc0[nt]); \
    acc0[nt] = MFMA(p##l0, b_h, acc0[nt]); \
    acc1[nt] = MFMA(p##h1, b_h, acc1[nt]); \
    acc1[nt] = MFMA(p##h1, b_l, acc1[nt]); \
    acc1[nt] = MFMA(p##l1, b_h, acc1[nt]); } }

  M_STAGE(0, 0); M_LOADA(aA, 0);
  for (int kb = 0; kb < 24; kb += 2) {
    M_STAGE(1, kb + 1); M_LOADA(aB, kb + 1);
    WAITBAR6();
    M_COMPUTE(0, aA);
    ENDBAR();
    if (kb < 22) { M_STAGE(0, kb + 2); M_LOADA(aA, kb + 2); WAITBAR6(); }
    else { WAITBAR0(); }
    M_COMPUTE(1, aB);
    ENDBAR();
  }
#define M_EPI(ACC, MT)                                                         \
  {                                                                            \
    _Pragma("unroll") for (int nt = 0; nt < 4; ++nt) {                         \
      int n = (nt0 + nt) * 16 + c;                                             \
      _Pragma("unroll") for (int r = 0; r < 4; ++r) {                          \
        int m = (MT) * 16 + 4 * g + r;                                         \
        float val = ACC[nt][r];                                                \
        if (MODE == 1)                                                         \
          val = 0.5f * val * (1.0f + fast_erf(val * 0.70710678118654752440f)); \
        int bi = m >> 8;                                                       \
        float t = ts[bi], s = ts[NBATCH + bi];                                 \
        uint32_t idx = (uint32_t)m * 768u + (uint32_t)n;                       \
        float u = tf_uniform(k0, k1, idx);                                     \
        val = (u < t) ? val * s : 0.0f;                                        \
        if (MODE == 1) {                                                       \
          unsigned short hh, hl;                                               \
          split2(val, hh, hl);                                                 \
          int kb2 = n >> 5;                                                    \
          int lane2 = (m & 15) + 16 * ((n & 31) >> 3);                         \
          int e2 = n & 7;                                                      \
          size_t word = ((size_t)(m >> 4) * 24 + kb2) * 64 + lane2;            \
          ((unsigned short *)oh)[word * 8 + e2] = hh;                          \
          ((unsigned short *)ol)[word * 8 + e2] = hl;                          \
        } else {                                                               \
          out[(size_t)m * 768 + n] = val;                                      \
        }                                                                      \
      }                                                                        \
    }                                                                          \
  }
  M_EPI(acc0, mt0)
  M_EPI(acc1, mt0 + 1)
#undef M_EPI
}

// ---------------- launch ----------------
extern "C" void kernel_launch(void *const *d_in, const int *in_sizes, int n_in,
                              void *d_out, int out_size, void *d_ws, size_t ws_size,
                              hipStream_t stream) {
  (void)in_sizes; (void)n_in; (void)out_size; (void)ws_size;
  const float *images = (const float *)d_in[0];
  const float *x  = (const float *)d_in[1];
  const float *w1 = (const float *)d_in[2];
  const float *w2 = (const float *)d_in[3];

  char *ws = (char *)d_ws;
  float   *win  = (float *)  (ws + WS_WIN);
  double  *bins = (double *) (ws + WS_BINS);
  float   *ts   = (float *)  (ws + WS_TS);
  uint8_t *bidx = (uint8_t *)(ws + WS_BIDX);
  short8  *tch  = (short8 *) (ws + WS_TW + 0 * TWSZ);
  short8  *tcl  = (short8 *) (ws + WS_TW + 1 * TWSZ);
  short8  *tsh  = (short8 *) (ws + WS_TW + 2 * TWSZ);
  short8  *tsl  = (short8 *) (ws + WS_TW + 3 * TWSZ);
  short8  *w1h  = (short8 *) (ws + WS_W + 0 * WSZ);
  short8  *w1l  = (short8 *) (ws + WS_W + 1 * WSZ);
  short8  *w2h  = (short8 *) (ws + WS_W + 2 * WSZ);
  short8  *w2l  = (short8 *) (ws + WS_W + 3 * WSZ);
  short8  *gh   = (short8 *) (ws + WS_REG1 + 0 * GSZ);
  short8  *gl   = (short8 *) (ws + WS_REG1 + 1 * GSZ);
  short8  *xh   = (short8 *) (ws + WS_REG1 + 0 * XSZ);
  short8  *xl   = (short8 *) (ws + WS_REG1 + 1 * XSZ);
  short8  *crh  = (short8 *) (ws + WS_REG2 + 0 * CBSZ);
  short8  *crl  = (short8 *) (ws + WS_REG2 + 1 * CBSZ);
  short8  *cih  = (short8 *) (ws + WS_REG2 + 2 * CBSZ);
  short8  *cil  = (short8 *) (ws + WS_REG2 + 3 * CBSZ);
  short8  *hh_  = (short8 *) (ws + WS_REG2 + 0 * XSZ);  // overwrites crX after k_cols
  short8  *hl_  = (short8 *) (ws + WS_REG2 + 1 * XSZ);
  float   *yout = (float *)d_out;

  uint32_t keys[6];
  tf2x32(0u, 1u, 0u, 0u, keys[0], keys[1]);
  tf2x32(0u, 1u, 0u, 1u, keys[2], keys[3]);
  tf2x32(0u, 1u, 0u, 2u, keys[4], keys[5]);

  k_prep<<<784, 256, 0, stream>>>(win, bins, bidx);
  k_tw<<<98, 256, 0, stream>>>(tch, tcl, tsh, tsl);
  k_wconv<<<dim3(288, 2), 256, 0, stream>>>(w1, w2, w1h, w1l, w2h, w2l);
  k_gprep<<<6272, 256, 0, stream>>>(images, win, gh, gl);
  k_rows<<<896, 256, 0, stream>>>(tch, tcl, tsh, tsl, gh, gl, crh, crl, cih, cil);
  k_cols<<<1680, 256, 0, stream>>>(tch, tcl, tsh, tsl, crh, crl, cih, cil, bidx, bins);
  k_probs<<<1, 64, 0, stream>>>(bins, ts);
  k_dropfrag<<<6144, 256, 0, stream>>>(x, ts, xh, xl, keys[0], keys[1]);
  k_mlp<1><<<1536, 256, 0, stream>>>(xh, xl, w1h, w1l, ts, yout, hh_, hl_, keys[2], keys[3]);
  k_mlp<2><<<1536, 256, 0, stream>>>(hh_, hl_, w2h, w2l, ts, yout, hh_, hl_, keys[4], keys[5]);
}

// Round 19
// 394.270 us; speedup vs baseline: 1.0815x; 1.0815x over previous
//
#include <hip/hip_runtime.h>
#include <stdint.h>
#include <math.h>

typedef __attribute__((ext_vector_type(8))) short short8;
typedef __attribute__((ext_vector_type(4))) float floatx4;

#define IMGN 448
#define HW   200704
#define NBATCH 64
#define NBINS 36

#define MFMA(a, b, c) __builtin_amdgcn_mfma_f32_16x16x32_bf16((a), (b), (c), 0, 0, 0)

// counted-vmcnt pipeline barriers (asm so the compiler can't force vmcnt(0))
#define WAITBAR8() asm volatile("s_waitcnt vmcnt(8)\ns_barrier" ::: "memory")
#define WAITBAR6() asm volatile("s_waitcnt vmcnt(6)\ns_barrier" ::: "memory")
#define WAITBAR0() asm volatile("s_waitcnt vmcnt(0)\ns_barrier" ::: "memory")
#define ENDBAR()   asm volatile("s_waitcnt lgkmcnt(0)\ns_barrier" ::: "memory")

// ---------------- workspace map (bytes) ----------------
#define WS_WIN   0u
#define WS_BINS  4096u
#define WS_TS    24576u
#define WS_BIDX  32768u
#define WS_TW    1048576u
#define TWSZ     401408u      // 28*14*64*16
#define WS_W     4194304u
#define WSZ      1179648u     // 48*24*64*16
#define WS_REG1  16777216u
#define GSZ      25690112u    // 1792*14*64*16
#define CBSZ     13762560u    // 960*14*64*16
#define XSZ      25165824u    // 1024*24*64*16
#define WS_REG2  75497472u
// REG1: G frags (2 x GSZ) -> xd frags (2 x XSZ, after rows)
// REG2: cols-B frags (4 x CBSZ, written by k_rows) -> h frags (2 x XSZ, after cols)

// ---------------- threefry2x32 (JAX partitionable) ----------------
__host__ __device__ __forceinline__ uint32_t rotl32(uint32_t v, int r) {
  return (v << r) | (v >> (32 - r));
}
__host__ __device__ __forceinline__ void tf2x32(uint32_t k0, uint32_t k1,
                                                uint32_t x0, uint32_t x1,
                                                uint32_t &o0, uint32_t &o1) {
  uint32_t k2 = k0 ^ k1 ^ 0x1BD11BDAu;
  uint32_t v0 = x0 + k0, v1 = x1 + k1;
#define TFR(r) { v0 += v1; v1 = rotl32(v1, r); v1 ^= v0; }
  TFR(13) TFR(15) TFR(26) TFR(6)   v0 += k1; v1 += k2 + 1u;
  TFR(17) TFR(29) TFR(16) TFR(24)  v0 += k2; v1 += k0 + 2u;
  TFR(13) TFR(15) TFR(26) TFR(6)   v0 += k0; v1 += k1 + 3u;
  TFR(17) TFR(29) TFR(16) TFR(24)  v0 += k1; v1 += k2 + 4u;
  TFR(13) TFR(15) TFR(26) TFR(6)   v0 += k2; v1 += k0 + 5u;
#undef TFR
  o0 = v0; o1 = v1;
}
__device__ __forceinline__ float tf_uniform(uint32_t k0, uint32_t k1, uint32_t idx) {
  uint32_t a, b;
  tf2x32(k0, k1, 0u, idx, a, b);
  uint32_t bits = a ^ b;
  return __uint_as_float((bits >> 9) | 0x3F800000u) - 1.0f;
}

// ---------------- bf16 split helpers ----------------
__device__ __forceinline__ unsigned short bf16rne(float v) {
  unsigned u = __float_as_uint(v);
  return (unsigned short)((u + 0x7fffu + ((u >> 16) & 1u)) >> 16);
}
__device__ __forceinline__ void split2(float v, unsigned short &h, unsigned short &l) {
  h = bf16rne(v);
  float fh = __uint_as_float(((unsigned)h) << 16);
  l = bf16rne(v - fh);
}

// branch-free erf (Abramowitz-Stegun 7.1.26, |abs err| <= 1.5e-7)
__device__ __forceinline__ float fast_erf(float x) {
  float ax = fabsf(x);
  float t = 1.0f / (1.0f + 0.3275911f * ax);
  float p = t * (0.254829592f + t * (-0.284496736f + t * (1.421413741f +
            t * (-1.453152027f + t * 1.061405429f))));
  float y = 1.0f - p * __expf(-ax * ax);
  return __uint_as_float((__float_as_uint(y) & 0x7fffffffu) |
                         (__float_as_uint(x) & 0x80000000u));
}

// async 16B/lane global->LDS; lds dst must be wave-uniform base (HW adds lane*16)
__device__ __forceinline__ void gload16(const void *g, void *l) {
  __builtin_amdgcn_global_load_lds(
      (const __attribute__((address_space(1))) unsigned int *)g,
      (__attribute__((address_space(3))) unsigned int *)l, 16, 0, 0);
}

// ---------------- prep ----------------
__global__ __launch_bounds__(256) void k_prep(float *__restrict__ win,
                                              double *__restrict__ bins,
                                              uint8_t *__restrict__ bidx) {
  int t = blockIdx.x * 256 + threadIdx.x;
  int a = t / IMGN, b = t % IMGN;
  double yy = (double)((a + 224) % IMGN) - 223.5;
  double xx = (double)((b + 224) % IMGN) - 223.5;
  double r2 = xx * xx + yy * yy;
  uint8_t idx = 255;
  if (r2 >= 249.76125 && r2 <= 90163.81125) {
    double th = atan2(yy, xx);
    if (th < 0.0) th += 6.283185307179586476925286766559;
    int i = (int)(th / 0.17453292519943295769236907684886);
    if (i > 35) i = 35;
    if (i < 0) i = 0;
    idx = (uint8_t)i;
  }
  bidx[t] = idx;
  if (t < IMGN) {
    double ang = 6.283185307179586476925286766559 * (double)t / 448.0;
    win[t] = (float)(0.5 - 0.5 * cos(ang));
  }
  if (t < NBATCH * NBINS) bins[t] = 0.0;
}

// ---------------- twiddle frag matrices (4) ----------------
__global__ __launch_bounds__(256) void k_tw(short8 *__restrict__ tch, short8 *__restrict__ tcl,
                                            short8 *__restrict__ tsh, short8 *__restrict__ tsl) {
  int wid = blockIdx.x * 256 + threadIdx.x;   // 25088 = 28*14*64
  int lane = wid & 63;
  int tmp = wid >> 6;
  int kb = tmp % 14, mb = tmp / 14;
  int m = mb * 16 + (lane & 15);
  int k0 = kb * 32 + (lane >> 4) * 8;
  short8 ch, cl, sh, sl;
#pragma unroll
  for (int e = 0; e < 8; ++e) {
    int mm = (m * (k0 + e)) % IMGN;
    double ang = -6.283185307179586476925286766559 * (double)mm / 448.0;
    float c = (float)cos(ang), s = (float)sin(ang);
    unsigned short h, l;
    split2(c, h, l); ch[e] = (short)h; cl[e] = (short)l;
    split2(s, h, l); sh[e] = (short)h; sl[e] = (short)l;
  }
  tch[wid] = ch; tcl[wid] = cl; tsh[wid] = sh; tsl[wid] = sl;
}

// ---------------- weight frag matrices ----------------
__global__ __launch_bounds__(256) void k_wconv(const float *__restrict__ w1, const float *__restrict__ w2,
                                               short8 *__restrict__ w1h, short8 *__restrict__ w1l,
                                               short8 *__restrict__ w2h, short8 *__restrict__ w2l) {
  int wid = blockIdx.x * 256 + threadIdx.x;   // 73728 = 48*24*64
  const float *src = blockIdx.y ? w2 : w1;
  short8 *dh = blockIdx.y ? w2h : w1h;
  short8 *dl = blockIdx.y ? w2l : w1l;
  int lane = wid & 63;
  int tmp = wid >> 6;
  int kb = tmp % 24, nb = tmp / 24;
  int n = nb * 16 + (lane & 15);
  int k0 = kb * 32 + (lane >> 4) * 8;
  const float *p = src + (size_t)n * 768 + k0;
  short8 vh, vl;
#pragma unroll
  for (int e = 0; e < 8; ++e) {
    unsigned short h, l;
    split2(p[e], h, l);
    vh[e] = (short)h; vl[e] = (short)l;
  }
  dh[wid] = vh; dl[wid] = vl;
}

// ---------------- windowed grayscale frag matrices ----------------
__global__ __launch_bounds__(256) void k_gprep(const float *__restrict__ img, const float *__restrict__ win,
                                               short8 *__restrict__ gh, short8 *__restrict__ gl) {
  int wid = blockIdx.x * 256 + threadIdx.x;   // 1605632 = 1792*14*64
  int lane = wid & 63;
  int tmp = wid >> 6;
  int kb = tmp % 14, nb = tmp / 14;
  int n = nb * 16 + (lane & 15);              // n = b*448 + y
  int b = n / 448, y = n % 448;
  int x0 = kb * 32 + (lane >> 4) * 8;
  const float *p = img + (size_t)b * 3 * HW + y * IMGN + x0;
  float wy = win[y];
  short8 vh, vl;
#pragma unroll
  for (int e = 0; e < 8; ++e) {
    float r = p[e], g = p[HW + e], bl = p[2 * HW + e];
    float t0 = (r * 0.229f + 0.485f) * 0.2989f;
    float t1 = (g * 0.224f + 0.456f) * 0.587f;
    float t2 = (bl * 0.225f + 0.406f) * 0.114f;
    float v = ((t0 + t1) + t2) * wy * win[x0 + e];
    unsigned short h, l;
    split2(v, h, l);
    vh[e] = (short)h; vl[e] = (short)l;
  }
  gh[wid] = vh; gl[wid] = vl;
}

// ---------------- rows GEMM: B(G) in LDS, A(twiddles) direct to regs --------
// grid 1792 = 4 mtg * 448 ntg, mtg fastest (shares B panel); 256 thr (4 waves)
__global__ __launch_bounds__(256) void k_rows(const short8 *__restrict__ tch, const short8 *__restrict__ tcl,
                                              const short8 *__restrict__ tsh, const short8 *__restrict__ tsl,
                                              const short8 *__restrict__ gh, const short8 *__restrict__ gl,
                                              short8 *__restrict__ crh, short8 *__restrict__ crl,
                                              short8 *__restrict__ cih, short8 *__restrict__ cil) {
  __shared__ short8 S[512];    // B: 2 mats x 4 nt (chunks 0..7)
  int orig = blockIdx.x;
  int swz = (orig & 7) * 224 + (orig >> 3);
  int mtg = swz & 3, ntg = swz >> 2;
  int tid = threadIdx.x;
  int lane = tid & 63, w = tid >> 6;
  int g = lane >> 4, c = lane & 15;
  int mt = mtg * 4 + w;
  floatx4 s_c[4] = {}, s_s[4] = {};
  for (int kb = 0; kb < 14; ++kb) {
#pragma unroll
    for (int i = 0; i < 2; ++i) {
      int ch = w * 2 + i;                 // 0..7: mat = ch>>2, nt = ch&3
      const short8 *m0 = (ch >> 2) ? gl : gh;
      int row = ntg * 4 + (ch & 3);
      gload16(m0 + ((size_t)row * 14 + kb) * 64 + lane, (char *)S + ch * 1024);
    }
    int ao = (mt * 14 + kb) * 64 + lane;  // per-wave A direct loads
    short8 ach = tch[ao], acl = tcl[ao], ash = tsh[ao], asl = tsl[ao];
    __syncthreads();
#pragma unroll
    for (int nt = 0; nt < 4; ++nt) {
      short8 bh = S[nt * 64 + lane];
      short8 bl = S[(4 + nt) * 64 + lane];
      s_c[nt] = MFMA(ach, bh, s_c[nt]);
      s_c[nt] = MFMA(ach, bl, s_c[nt]);
      s_c[nt] = MFMA(acl, bh, s_c[nt]);
      s_s[nt] = MFMA(ash, bh, s_s[nt]);
      s_s[nt] = MFMA(ash, bl, s_s[nt]);
      s_s[nt] = MFMA(asl, bh, s_s[nt]);
    }
    __syncthreads();
  }
  // epilogue: split in-register and scatter into cols-B frag layout
#pragma unroll
  for (int nt = 0; nt < 4; ++nt) {
    int nrow = (ntg * 4 + nt) * 16 + c;     // = b*448 + y
    int b = nrow / 448, y = nrow % 448;
    int kb2 = y >> 5;
    int lofs = 16 * ((y & 31) >> 3);
    int e2 = y & 7;
#pragma unroll
    for (int r = 0; r < 4; ++r) {
      int v = mt * 16 + 4 * g + r;
      if (v < 240) {
        int n2 = b * 240 + v;
        size_t word = ((size_t)(n2 >> 4) * 14 + kb2) * 64 + (n2 & 15) + lofs;
        unsigned short h, l;
        split2(s_c[nt][r], h, l);
        ((unsigned short *)crh)[word * 8 + e2] = h;
        ((unsigned short *)crl)[word * 8 + e2] = l;
        split2(s_s[nt][r], h, l);
        ((unsigned short *)cih)[word * 8 + e2] = h;
        ((unsigned short *)cil)[word * 8 + e2] = l;
      }
    }
  }
}

// ---------------- cols GEMM: counted-vmcnt 2-deep pipeline, fused binning ----
// grid 1680 = 7 mtg * 240 ntg, mtg fastest (shares B panel); 256 thr (4 waves)
__global__ __launch_bounds__(256) void k_cols(const short8 *__restrict__ tch, const short8 *__restrict__ tcl,
                                              const short8 *__restrict__ tsh, const short8 *__restrict__ tsl,
                                              const short8 *__restrict__ crh, const short8 *__restrict__ crl,
                                              const short8 *__restrict__ cih, const short8 *__restrict__ cil,
                                              const uint8_t *__restrict__ bidx, double *__restrict__ bins) {
  __shared__ short8 S[2][1024];  // B: 4 mats x 4 nt per buffer
  __shared__ double lb[72];
  int orig = blockIdx.x;
  int swz = (orig & 7) * 210 + (orig >> 3);
  int mtg = swz % 7, ntg = swz / 7;
  int tid = threadIdx.x;
  if (tid < 72) lb[tid] = 0.0;
  int lane = tid & 63, w = tid >> 6;
  int g = lane >> 4, c = lane & 15;
  int mt = mtg * 4 + w;
  int nt0 = ntg * 4;
  floatx4 s_cc[4] = {}, s_sc[4] = {}, s_ss[4] = {}, s_cs[4] = {};
  short8 aAc, aAcl, aAs, aAsl, aBc, aBcl, aBs, aBsl;

#define C_STAGE(buf, kb) { \
  _Pragma("unroll") for (int i = 0; i < 4; ++i) { \
    int ch = w * 4 + i; int sel = ch >> 2; \
    const short8 *m0 = sel == 0 ? crh : sel == 1 ? crl : sel == 2 ? cih : cil; \
    int row = nt0 + (ch & 3); \
    gload16(m0 + ((size_t)row * 14 + (kb)) * 64 + lane, (char *)&S[buf][0] + ch * 1024); } }
#define C_LOADA(p, kb) { int ao = (mt * 14 + (kb)) * 64 + lane; \
  p##c = tch[ao]; p##cl = tcl[ao]; p##s = tsh[ao]; p##sl = tsl[ao]; }
#define C_COMPUTE(buf, p) { const short8 *Sc = &S[buf][0]; \
  _Pragma("unroll") for (int nt = 0; nt < 4; ++nt) { \
    short8 brh = Sc[nt * 64 + lane]; \
    short8 brl = Sc[(4 + nt) * 64 + lane]; \
    short8 bih = Sc[(8 + nt) * 64 + lane]; \
    short8 bil = Sc[(12 + nt) * 64 + lane]; \
    s_cc[nt] = MFMA(p##c, brh, s_cc[nt]); \
    s_cc[nt] = MFMA(p##c, brl, s_cc[nt]); \
    s_cc[nt] = MFMA(p##cl, brh, s_cc[nt]); \
    s_sc[nt] = MFMA(p##s, brh, s_sc[nt]); \
    s_sc[nt] = MFMA(p##s, brl, s_sc[nt]); \
    s_sc[nt] = MFMA(p##sl, brh, s_sc[nt]); \
    s_ss[nt] = MFMA(p##s, bih, s_ss[nt]); \
    s_ss[nt] = MFMA(p##s, bil, s_ss[nt]); \
    s_ss[nt] = MFMA(p##sl, bih, s_ss[nt]); \
    s_cs[nt] = MFMA(p##c, bih, s_cs[nt]); \
    s_cs[nt] = MFMA(p##c, bil, s_cs[nt]); \
    s_cs[nt] = MFMA(p##cl, bih, s_cs[nt]); } }

  C_STAGE(0, 0); C_LOADA(aA, 0);
  for (int kb = 0; kb < 14; kb += 2) {
    C_STAGE(1, kb + 1); C_LOADA(aB, kb + 1);
    WAITBAR8();
    C_COMPUTE(0, aA);
    ENDBAR();
    if (kb < 12) { C_STAGE(0, kb + 2); C_LOADA(aA, kb + 2); WAITBAR8(); }
    else { WAITBAR0(); }
    C_COMPUTE(1, aB);
    ENDBAR();
  }
  // binning epilogue with per-thread 4-entry MRU cache (static reg indexing)
  int base_b = (ntg * 64) / 240;
  int cb0 = -1, cb1 = -1, cb2 = -1, cb3 = -1;
  double cv0 = 0.0, cv1 = 0.0, cv2 = 0.0, cv3 = 0.0;
#define PUTBIN(slot_, val_)                                                    \
  { int _s = (slot_); double _v = (val_);                                      \
    if (_s == cb0) cv0 += _v;                                                  \
    else if (_s == cb1) cv1 += _v;                                             \
    else if (_s == cb2) cv2 += _v;                                             \
    else if (_s == cb3) cv3 += _v;                                             \
    else {                                                                     \
      if (cb3 >= 0) atomicAdd(&lb[cb3], cv3);                                  \
      cb3 = cb2; cv3 = cv2; cb2 = cb1; cv2 = cv1;                              \
      cb1 = cb0; cv1 = cv0; cb0 = _s; cv0 = _v;                                \
    } }
#pragma unroll
  for (int nt = 0; nt < 4; ++nt) {
    int n = (nt0 + nt) * 16 + c;            // n = b*240 + v
    int v = n % 240;
    int bloc = n / 240 - base_b;
    if (v < 225) {
#pragma unroll
      for (int r = 0; r < 4; ++r) {
        int u = mt * 16 + 4 * g + r;
        float frv = s_cc[nt][r] - s_ss[nt][r];
        float fiv = s_sc[nt][r] + s_cs[nt][r];
        double P = (double)frv * frv + (double)fiv * fiv;
        int i1 = bidx[u * IMGN + v];
        if (i1 < 36) PUTBIN(bloc * 36 + i1, P);
        if (v >= 1 && v <= 223) {
          int i2 = bidx[((IMGN - u) % IMGN) * IMGN + (IMGN - v)];
          if (i2 < 36) PUTBIN(bloc * 36 + i2, P);
        }
      }
    }
  }
  if (cb0 >= 0) atomicAdd(&lb[cb0], cv0);
  if (cb1 >= 0) atomicAdd(&lb[cb1], cv1);
  if (cb2 >= 0) atomicAdd(&lb[cb2], cv2);
  if (cb3 >= 0) atomicAdd(&lb[cb3], cv3);
#undef PUTBIN
  __syncthreads();
  if (tid < 72) {
    int bb = base_b + tid / 36;
    if (bb < NBATCH && lb[tid] != 0.0) atomicAdd(&bins[bb * NBINS + (tid % 36)], lb[tid]);
  }
}

// ---------------- entropy -> ape -> drop prob ----------------
__global__ void k_probs(const double *__restrict__ bins, float *__restrict__ ts) {
  int b = threadIdx.x;
  if (b >= NBATCH) return;
  double T = 0.0;
  for (int i = 0; i < NBINS; ++i) T += bins[b * NBINS + i];
  double H = 0.0;
  for (int i = 0; i < NBINS; ++i) {
    double p = bins[b * NBINS + i] / (T + 1e-12);
    H -= p * log(p + 1e-12);
  }
  double ape = H / 3.5835189384561099;
  if (ape > 1.0) ape = 1.0;
  if (ape < 0.0) ape = 0.0;
  if (T <= 1e-12) ape = 0.0;
  double adj = tanh((0.78 - ape) * 4.0);
  double drop = (adj >= 0.0) ? (0.3 + adj * 0.3) : (0.3 + adj * 0.2);
  if (drop < 0.1) drop = 0.1;
  if (drop > 0.6) drop = 0.6;
  float p32 = (float)drop;
  ts[b] = 1.0f - p32;
  ts[NBATCH + b] = 1.0f / (1.0f - p32 + 1e-8f);
}

// ---------------- dropout(x) -> A-frag split mats ----------------
__global__ __launch_bounds__(256) void k_dropfrag(const float *__restrict__ x, const float *__restrict__ ts,
                                                  short8 *__restrict__ xh, short8 *__restrict__ xl,
                                                  uint32_t k0, uint32_t k1) {
  int wid = blockIdx.x * 256 + threadIdx.x;   // 1572864 = 1024*24*64
  int lane = wid & 63;
  int tmp = wid >> 6;
  int kb = tmp % 24, mb = tmp / 24;
  int m = mb * 16 + (lane & 15);
  int d0 = kb * 32 + (lane >> 4) * 8;
  int bi = m >> 8;
  float t = ts[bi], s = ts[NBATCH + bi];
  const float *p = x + (size_t)m * 768 + d0;
  short8 vh, vl;
#pragma unroll
  for (int e = 0; e < 8; ++e) {
    uint32_t idx = (uint32_t)m * 768u + (uint32_t)(d0 + e);
    float u = tf_uniform(k0, k1, idx);
    float v = (u < t) ? p[e] * s : 0.0f;
    unsigned short h, l;
    split2(v, h, l);
    vh[e] = (short)h; vl[e] = (short)l;
  }
  xh[wid] = vh; xl[wid] = vl;
}

// ---------------- MLP GEMM: 2 mtiles/wave, counted-vmcnt 2-deep pipeline -----
// grid 1536 = 12 ntg * 128 mtg, ntg fastest (shares A panel); 256 thr (4 waves)
template <int MODE>
__global__ __launch_bounds__(256) void k_mlp(const short8 *__restrict__ ah, const short8 *__restrict__ al,
                                             const short8 *__restrict__ bh, const short8 *__restrict__ bl,
                                             const float *__restrict__ ts, float *__restrict__ out,
                                             short8 *__restrict__ oh, short8 *__restrict__ ol,
                                             uint32_t k0, uint32_t k1) {
  __shared__ short8 S[2][512];   // B: 2 mats x 4 nt per buffer
  int orig = blockIdx.x;
  int swz = (orig & 7) * 192 + (orig >> 3);
  int ntg = swz % 12, mtg = swz / 12;
  int tid = threadIdx.x;
  int lane = tid & 63, w = tid >> 6;
  int g = lane >> 4, c = lane & 15;
  int mt0 = mtg * 8 + w * 2;    // this wave's 2 mtiles: mt0, mt0+1
  int nt0 = ntg * 4;
  floatx4 acc0[4] = {}, acc1[4] = {};
  short8 aAh0, aAl0, aAh1, aAl1, aBh0, aBl0, aBh1, aBl1;

#define M_STAGE(buf, kb) { \
  _Pragma("unroll") for (int i = 0; i < 2; ++i) { \
    int ch = w * 2 + i; \
    const short8 *m0 = (ch >> 2) ? bl : bh; \
    int row = nt0 + (ch & 3); \
    gload16(m0 + ((size_t)row * 24 + (kb)) * 64 + lane, (char *)&S[buf][0] + ch * 1024); } }
#define M_LOADA(p, kb) { int ao = (mt0 * 24 + (kb)) * 64 + lane; \
  p##h0 = ah[ao]; p##l0 = al[ao]; \
  p##h1 = ah[ao + 24 * 64]; p##l1 = al[ao + 24 * 64]; }
#define M_COMPUTE(buf, p) { const short8 *Sc = &S[buf][0]; \
  _Pragma("unroll") for (int nt = 0; nt < 4; ++nt) { \
    short8 b_h = Sc[nt * 64 + lane]; \
    short8 b_l = Sc[(4 + nt) * 64 + lane]; \
    acc0[nt] = MFMA(p##h0, b_h, acc0[nt]); \
    acc0[nt] = MFMA(p##h0, b_l, acc0[nt]); \
    acc0[nt] = MFMA(p##l0, b_h, acc0[nt]); \
    acc1[nt] = MFMA(p##h1, b_h, acc1[nt]); \
    acc1[nt] = MFMA(p##h1, b_l, acc1[nt]); \
    acc1[nt] = MFMA(p##l1, b_h, acc1[nt]); } }

  M_STAGE(0, 0); M_LOADA(aA, 0);
  for (int kb = 0; kb < 24; kb += 2) {
    M_STAGE(1, kb + 1); M_LOADA(aB, kb + 1);
    WAITBAR6();
    M_COMPUTE(0, aA);
    ENDBAR();
    if (kb < 22) { M_STAGE(0, kb + 2); M_LOADA(aA, kb + 2); WAITBAR6(); }
    else { WAITBAR0(); }
    M_COMPUTE(1, aB);
    ENDBAR();
  }
#define M_EPI(ACC, MT)                                                         \
  {                                                                            \
    _Pragma("unroll") for (int nt = 0; nt < 4; ++nt) {                         \
      int n = (nt0 + nt) * 16 + c;                                             \
      _Pragma("unroll") for (int r = 0; r < 4; ++r) {                          \
        int m = (MT) * 16 + 4 * g + r;                                         \
        float val = ACC[nt][r];                                                \
        if (MODE == 1)                                                         \
          val = 0.5f * val * (1.0f + fast_erf(val * 0.70710678118654752440f)); \
        int bi = m >> 8;                                                       \
        float t = ts[bi], s = ts[NBATCH + bi];                                 \
        uint32_t idx = (uint32_t)m * 768u + (uint32_t)n;                       \
        float u = tf_uniform(k0, k1, idx);                                     \
        val = (u < t) ? val * s : 0.0f;                                        \
        if (MODE == 1) {                                                       \
          unsigned short hh, hl;                                               \
          split2(val, hh, hl);                                                 \
          int kb2 = n >> 5;                                                    \
          int lane2 = (m & 15) + 16 * ((n & 31) >> 3);                         \
          int e2 = n & 7;                                                      \
          size_t word = ((size_t)(m >> 4) * 24 + kb2) * 64 + lane2;            \
          ((unsigned short *)oh)[word * 8 + e2] = hh;                          \
          ((unsigned short *)ol)[word * 8 + e2] = hl;                          \
        } else {                                                               \
          out[(size_t)m * 768 + n] = val;                                      \
        }                                                                      \
      }                                                                        \
    }                                                                          \
  }
  M_EPI(acc0, mt0)
  M_EPI(acc1, mt0 + 1)
#undef M_EPI
}

// ---------------- launch ----------------
extern "C" void kernel_launch(void *const *d_in, const int *in_sizes, int n_in,
                              void *d_out, int out_size, void *d_ws, size_t ws_size,
                              hipStream_t stream) {
  (void)in_sizes; (void)n_in; (void)out_size; (void)ws_size;
  const float *images = (const float *)d_in[0];
  const float *x  = (const float *)d_in[1];
  const float *w1 = (const float *)d_in[2];
  const float *w2 = (const float *)d_in[3];

  char *ws = (char *)d_ws;
  float   *win  = (float *)  (ws + WS_WIN);
  double  *bins = (double *) (ws + WS_BINS);
  float   *ts   = (float *)  (ws + WS_TS);
  uint8_t *bidx = (uint8_t *)(ws + WS_BIDX);
  short8  *tch  = (short8 *) (ws + WS_TW + 0 * TWSZ);
  short8  *tcl  = (short8 *) (ws + WS_TW + 1 * TWSZ);
  short8  *tsh  = (short8 *) (ws + WS_TW + 2 * TWSZ);
  short8  *tsl  = (short8 *) (ws + WS_TW + 3 * TWSZ);
  short8  *w1h  = (short8 *) (ws + WS_W + 0 * WSZ);
  short8  *w1l  = (short8 *) (ws + WS_W + 1 * WSZ);
  short8  *w2h  = (short8 *) (ws + WS_W + 2 * WSZ);
  short8  *w2l  = (short8 *) (ws + WS_W + 3 * WSZ);
  short8  *gh   = (short8 *) (ws + WS_REG1 + 0 * GSZ);
  short8  *gl   = (short8 *) (ws + WS_REG1 + 1 * GSZ);
  short8  *xh   = (short8 *) (ws + WS_REG1 + 0 * XSZ);
  short8  *xl   = (short8 *) (ws + WS_REG1 + 1 * XSZ);
  short8  *crh  = (short8 *) (ws + WS_REG2 + 0 * CBSZ);
  short8  *crl  = (short8 *) (ws + WS_REG2 + 1 * CBSZ);
  short8  *cih  = (short8 *) (ws + WS_REG2 + 2 * CBSZ);
  short8  *cil  = (short8 *) (ws + WS_REG2 + 3 * CBSZ);
  short8  *hh_  = (short8 *) (ws + WS_REG2 + 0 * XSZ);  // overwrites crX after k_cols
  short8  *hl_  = (short8 *) (ws + WS_REG2 + 1 * XSZ);
  float   *yout = (float *)d_out;

  uint32_t keys[6];
  tf2x32(0u, 1u, 0u, 0u, keys[0], keys[1]);
  tf2x32(0u, 1u, 0u, 1u, keys[2], keys[3]);
  tf2x32(0u, 1u, 0u, 2u, keys[4], keys[5]);

  k_prep<<<784, 256, 0, stream>>>(win, bins, bidx);
  k_tw<<<98, 256, 0, stream>>>(tch, tcl, tsh, tsl);
  k_wconv<<<dim3(288, 2), 256, 0, stream>>>(w1, w2, w1h, w1l, w2h, w2l);
  k_gprep<<<6272, 256, 0, stream>>>(images, win, gh, gl);
  k_rows<<<1792, 256, 0, stream>>>(tch, tcl, tsh, tsl, gh, gl, crh, crl, cih, cil);
  k_cols<<<1680, 256, 0, stream>>>(tch, tcl, tsh, tsl, crh, crl, cih, cil, bidx, bins);
  k_probs<<<1, 64, 0, stream>>>(bins, ts);
  k_dropfrag<<<6144, 256, 0, stream>>>(x, ts, xh, xl, keys[0], keys[1]);
  k_mlp<1><<<1536, 256, 0, stream>>>(xh, xl, w1h, w1l, ts, yout, hh_, hl_, keys[2], keys[3]);
  k_mlp<2><<<1536, 256, 0, stream>>>(hh_, hl_, w2h, w2l, ts, yout, hh_, hl_, keys[4], keys[5]);
}